// Round 12
// baseline (229.716 us; speedup 1.0000x reference)
//
#include <hip/hip_runtime.h>

#define BATCH 8
#define SEQ   8192
#define NH    16
#define DP    64
#define DN    64
#define ROWF  (NH*DP)        // 1024 floats per t (all heads)

// ---------------------------------------------------------------------------
// k_partial: ONE WAVE per (b, h, chunk). No LDS, no barriers (rounds 2-11
// showed the block-wide lgkm+barrier per tile is the latency wall: ~190us
// even with inputs L3-resident at 350 GB/s HBM). Lane loads exactly the 8
// X-floats / 8 B-floats it consumes (8-lane broadcast loads), 2-t-deep
// register prefetch with static even/odd sets, waves fully independent.
// partial[p][n] = sum_t exp(chunkTotal - cumsum_t) * X[t][p] * B[t][n]
// ---------------------------------------------------------------------------
template<int NBLK>
__global__ __launch_bounds__(256)
void k_partial(const float* __restrict__ Xg, const float* __restrict__ Ag,
               const float* __restrict__ Bg, float* __restrict__ part,
               float* __restrict__ blockA)
{
    constexpr int TB = SEQ / NBLK;      // 256 (NBLK=32) or 512 (NBLK=16)
    constexpr int Q  = TB / 64;         // t's per lane in scan / per group: 4 or 8

    const int tid  = threadIdx.x;
    const int lane = tid & 63;
    const int widx = blockIdx.x * 4 + (tid >> 6);   // global wave index
    const int h    = widx & (NH - 1);
    const int bc   = widx >> 4;                     // b*NBLK + blk
    const int blk  = bc % NBLK;
    const int b    = bc / NBLK;
    const int t0   = blk * TB;

    // ---- per-wave scan of A column h over this chunk ----
    float c[Q];
    {
        const size_t abase = ((size_t)(b * SEQ + t0 + lane * Q)) * NH + h;
        float run = 0.f;
        #pragma unroll
        for (int k = 0; k < Q; ++k) { run += Ag[abase + (size_t)k * NH]; c[k] = run; }
    }
    float tsum = c[Q - 1], s = tsum;
    #pragma unroll
    for (int d = 1; d < 64; d <<= 1) {
        float o = __shfl_up(s, d, 64);
        if (lane >= d) s += o;
    }
    const float total = __shfl(s, 63, 64);
    const float excl  = s - tsum;
    float wv[Q];                         // weight of t=g*Q+k lives in lane g, reg k
    #pragma unroll
    for (int k = 0; k < Q; ++k) wv[k] = __expf(total - (excl + c[k]));
    if (lane == 63) blockA[(size_t)(b * NH + h) * NBLK + blk] = total;

    // ---- accumulator ----
    float acc[8][8];
    #pragma unroll
    for (int i = 0; i < 8; ++i)
        #pragma unroll
        for (int j = 0; j < 8; ++j) acc[i][j] = 0.f;

    const int p0F = (lane >> 3) << 3;    // this lane's 8 p's
    const int n0F = (lane & 7) << 3;     // this lane's 8 n's

    // 32-bit element indices (X is 268MB = 67M floats < 2^31)
    const unsigned xb32 = (unsigned)((b * SEQ + t0) * ROWF + h * DP);
    unsigned offX0 = xb32 + p0F;               // even-t set
    unsigned offB0 = xb32 + n0F;
    unsigned offX1 = offX0 + ROWF;             // odd-t set
    unsigned offB1 = offB0 + ROWF;

    // prologue: load t=0 into S0, t=1 into S1
    float4 s0x0 = *(const float4*)(Xg + offX0);
    float4 s0x1 = *(const float4*)(Xg + offX0 + 4);
    float4 s0b0 = *(const float4*)(Bg + offB0);
    float4 s0b1 = *(const float4*)(Bg + offB0 + 4);
    float4 s1x0 = *(const float4*)(Xg + offX1);
    float4 s1x1 = *(const float4*)(Xg + offX1 + 4);
    float4 s1b0 = *(const float4*)(Bg + offB1);
    float4 s1b1 = *(const float4*)(Bg + offB1 + 4);

    // body(t): consume set, reload it for t+2. xs copies let the X-reload
    // issue before the FMAs; B-reload issues after (B regs feed FMAs直接).
    auto bodyS0 = [&](float wt, bool reload) {
        const float xs[8] = { s0x0.x * wt, s0x0.y * wt, s0x0.z * wt, s0x0.w * wt,
                              s0x1.x * wt, s0x1.y * wt, s0x1.z * wt, s0x1.w * wt };
        if (reload) {
            offX0 += 2 * ROWF;
            s0x0 = *(const float4*)(Xg + offX0);
            s0x1 = *(const float4*)(Xg + offX0 + 4);
        }
        const float bs[8] = { s0b0.x, s0b0.y, s0b0.z, s0b0.w,
                              s0b1.x, s0b1.y, s0b1.z, s0b1.w };
        #pragma unroll
        for (int i = 0; i < 8; ++i)
            #pragma unroll
            for (int j = 0; j < 8; ++j)
                acc[i][j] = fmaf(xs[i], bs[j], acc[i][j]);
        if (reload) {
            offB0 += 2 * ROWF;
            s0b0 = *(const float4*)(Bg + offB0);
            s0b1 = *(const float4*)(Bg + offB0 + 4);
        }
    };
    auto bodyS1 = [&](float wt, bool reload) {
        const float xs[8] = { s1x0.x * wt, s1x0.y * wt, s1x0.z * wt, s1x0.w * wt,
                              s1x1.x * wt, s1x1.y * wt, s1x1.z * wt, s1x1.w * wt };
        if (reload) {
            offX1 += 2 * ROWF;
            s1x0 = *(const float4*)(Xg + offX1);
            s1x1 = *(const float4*)(Xg + offX1 + 4);
        }
        const float bs[8] = { s1b0.x, s1b0.y, s1b0.z, s1b0.w,
                              s1b1.x, s1b1.y, s1b1.z, s1b1.w };
        #pragma unroll
        for (int i = 0; i < 8; ++i)
            #pragma unroll
            for (int j = 0; j < 8; ++j)
                acc[i][j] = fmaf(xs[i], bs[j], acc[i][j]);
        if (reload) {
            offB1 += 2 * ROWF;
            s1b0 = *(const float4*)(Bg + offB1);
            s1b1 = *(const float4*)(Bg + offB1 + 4);
        }
    };

    // 64 groups of Q t's; weight source lane = g (uniform). Full reload for
    // g<63; tail group reloads only while target t+2 stays in-chunk (k<Q-2).
    for (int g = 0; g < 63; ++g) {
        #pragma unroll
        for (int k = 0; k < Q; ++k) {
            const float wt = __shfl(wv[k], g, 64);
            if (k & 1) bodyS1(wt, true);
            else       bodyS0(wt, true);
        }
    }
    {
        const int g = 63;
        #pragma unroll
        for (int k = 0; k < Q; ++k) {
            const float wt = __shfl(wv[k], g, 64);
            if (k & 1) bodyS1(wt, k < Q - 2);
            else       bodyS0(wt, k < Q - 2);
        }
    }

    // ---- epilogue: acc rows are n-contiguous -> float4 stores
    float* dst = part + ((size_t)(b * NH + h) * NBLK + blk) * 4096;
    #pragma unroll
    for (int i = 0; i < 8; ++i) {
        float4 lo = make_float4(acc[i][0], acc[i][1], acc[i][2], acc[i][3]);
        float4 hi = make_float4(acc[i][4], acc[i][5], acc[i][6], acc[i][7]);
        *(float4*)&dst[(p0F + i) * 64 + n0F]     = lo;
        *(float4*)&dst[(p0F + i) * 64 + n0F + 4] = hi;
    }
}

// ---------------------------------------------------------------------------
// k_scales: suffix-exp over chunk totals, per (b,h)
// ---------------------------------------------------------------------------
__global__ void k_scales(const float* __restrict__ blockA, float* __restrict__ scale,
                         int nblk)
{
    const int bh = blockIdx.x * blockDim.x + threadIdx.x;
    if (bh < BATCH * NH) {
        float run = 0.f;
        for (int c2 = nblk - 1; c2 >= 0; --c2) {
            scale[bh * nblk + c2] = __expf(run);
            run += blockA[bh * nblk + c2];
        }
    }
}

// ---------------------------------------------------------------------------
// k_combine: out[bh,p,n] = sum_c scale[bh,c] * part[bh,c,p,n]
// ---------------------------------------------------------------------------
__global__ __launch_bounds__(256)
void k_combine(const float* __restrict__ part, const float* __restrict__ scale,
               float* __restrict__ out, int nblk)
{
    const int idx = blockIdx.x * 256 + threadIdx.x;   // 0..524287
    const int bh  = idx >> 12;
    const int e   = idx & 4095;
    float r = 0.f;
    for (int q = 0; q < nblk; ++q)
        r += scale[bh * nblk + q] * part[((size_t)bh * nblk + q) * 4096 + e];
    out[idx] = r;
}

// ---------------------------------------------------------------------------
extern "C" void kernel_launch(void* const* d_in, const int* in_sizes, int n_in,
                              void* d_out, int out_size, void* d_ws, size_t ws_size,
                              hipStream_t stream)
{
    const float* X = (const float*)d_in[0];
    const float* A = (const float*)d_in[1];
    const float* B = (const float*)d_in[2];
    float* out     = (float*)d_out;

    // ws need for NBLK chunks: part (8*16*NBLK*4096 f32) + blockA + scale
    const size_t need32 = ((size_t)BATCH * NH * 32 * 4096 + 2ull * BATCH * NH * 32) * 4;
    const int nblk = (ws_size >= need32) ? 32 : 16;

    float* part   = (float*)d_ws;
    float* blockA = part + (size_t)BATCH * NH * nblk * 4096;
    float* scale  = blockA + (size_t)BATCH * NH * nblk;

    if (nblk == 32)
        hipLaunchKernelGGL((k_partial<32>), dim3(BATCH * NH * 32 / 4), dim3(256), 0, stream,
                           X, A, B, part, blockA);
    else
        hipLaunchKernelGGL((k_partial<16>), dim3(BATCH * NH * 16 / 4), dim3(256), 0, stream,
                           X, A, B, part, blockA);

    hipLaunchKernelGGL(k_scales, dim3(1), dim3(128), 0, stream, blockA, scale, nblk);
    hipLaunchKernelGGL(k_combine, dim3((BATCH * NH * 4096) / 256), dim3(256), 0, stream,
                       part, scale, out, nblk);
}